// Round 1
// baseline (257.594 us; speedup 1.0000x reference)
//
#include <hip/hip_runtime.h>

// ---------------------------------------------------------------------------
// VM-LSTM cell, B=8192, D=H=1024, G=2, WR=64, URANKS=[64,64]
//
//   prep : stage-1 weights in MFMA-frag-major fp16 (U1f: x@Ux, Uh1f: 4 h-mats);
//          stage-2 weight W2f frag-major fp16; correction vectors cx/ch/bb
//          (v5: wave-parallel — one wave per element, shfl_xor reduce).
//   s1   : 16-row blocks, grid (512,3). A-tile (x or h chunk) in LDS,
//          B-frags straight from global (L2-hot, coalesced 1KB/load).
//   s2 v5: 32-row x 64-col blocks, grid (256,16) = 4096. Barrier-free,
//          LDS-free: A-frags read straight from Ta/Tb in global (L2/L3-hot,
//          16x64B fully-used lines per 1KB wave load); each B-frag feeds
//          2 MFMAs (two 16-row tiles). Epilogue x/h/c loads batch-issued
//          BEFORE the MFMA loop (force MLP; compiler was serializing them
//          at VGPR=52). rcp-based sigmoid/tanh epilogue unchanged.
// Gates: sg=0 i, 1 f (use Ta); 2 o, 3 n (use Tb). jx(q)=q, jh(q)=q^1.
// ---------------------------------------------------------------------------

typedef _Float16 half8 __attribute__((ext_vector_type(8)));
typedef _Float16 half4v __attribute__((ext_vector_type(4)));
typedef float f32x4 __attribute__((ext_vector_type(4)));

// workspace offsets (bytes)
#define WS_TA    0                     // 8192*192 fp16 = 3145728
#define WS_TB    3145728
#define WS_U1F   6291456               // 131072 B
#define WS_UH1F  6422528               // 262144 B
#define WS_W2    6684672               // 1572864 B (frag-major)
#define WS_CX    8257536               // 4096 fp32
#define WS_CH    8273920
#define WS_BB    8290304

// ---------------------------------------------------------------------------
__global__ __launch_bounds__(256) void prep_kernel(
    const float* __restrict__ Ux, const float* __restrict__ Vx,
    const float* __restrict__ Uh0, const float* __restrict__ Vh0,
    const float* __restrict__ Uh1, const float* __restrict__ Vh1,
    const float* __restrict__ dia_x, const float* __restrict__ dia_h,
    const float* __restrict__ bias_x, const float* __restrict__ bias_h,
    _Float16* __restrict__ U1f, _Float16* __restrict__ Uh1f,
    _Float16* __restrict__ W2f, float* __restrict__ cx,
    float* __restrict__ ch, float* __restrict__ bb)
{
    int e = blockIdx.x * 256 + threadIdx.x;
    if (e < 8192) {
        // U1f[ct(4)][ks(32)][lane][8]: B-frag for x@Ux.
        int lane = e & 63, ks = (e >> 6) & 31, ct = e >> 11;
        int l15 = lane & 15, quad = lane >> 4;
        half8 v8;
        #pragma unroll
        for (int jj = 0; jj < 8; ++jj) {
            int k = ks * 32 + quad * 8 + jj;
            v8[jj] = (_Float16)Ux[k * 64 + ct * 16 + l15];
        }
        *(half8*)&U1f[(size_t)e * 8] = v8;
    } else if (e < 24576) {
        // Uh1f[j(4)][ct(4)][ks(16)][lane][8]; j: 0=Uh0g0,1=Uh1g0,2=Uh0g1,3=Uh1g1
        int t = e - 8192;
        int lane = t & 63, ks = (t >> 6) & 15, ct = (t >> 10) & 3, j = t >> 12;
        int l15 = lane & 15, quad = lane >> 4;
        const float* src = (j & 1) ? Uh1 : Uh0;
        int g = j >> 1;
        half8 v8;
        #pragma unroll
        for (int jj = 0; jj < 8; ++jj) {
            int k = ks * 32 + quad * 8 + jj;
            v8[jj] = (_Float16)src[(g * 512 + k) * 64 + ct * 16 + l15];
        }
        *(half8*)&Uh1f[(size_t)t * 8] = v8;
    } else if (e < 122880) {
        // W2f fragment-major: t = (((s*2+g01)*64 + ct)*6 + ks)*64 + lane
        int t = e - 24576;                 // 0..98303
        int lane = t & 63;
        int ksq  = (t >> 6) % 6;
        int ct   = (t / 384) & 63;
        int g01  = (t / 24576) & 1;
        int s    = t / 49152;
        int l15 = lane & 15, quad = lane >> 4;
        int k = ct * 16 + l15;             // output column
        int jx = s * 2 + g01;
        int m = (g01 == 0) ? (1024 + k) : k;
        half8 v8;
        #pragma unroll
        for (int jj = 0; jj < 8; ++jj) {
            int kk = ksq * 32 + quad * 8 + jj;   // K index 0..191
            int r = kk & 63, sect = kk >> 6;
            float val;
            if (sect == 0)      val = Vx[(jx * 1024 + k) * 64 + r];
            else if (sect == 1) val = Vh0[(s * 64 + r) * 2048 + m];
            else                val = Vh1[(s * 64 + r) * 2048 + m];
            v8[jj] = (_Float16)val;
        }
        *(half8*)&W2f[(size_t)t * 8] = v8;
    } else {
        // correction vectors, wave-parallel: one wave per element t, lane = r.
        // t = q*1024+k, q in {0:i,1:f,2:o,3:n}. 262144 threads = 4096 waves.
        int t64 = e - 122880;              // 0..262143
        int t = t64 >> 6;                  // 0..4095
        int r = t64 & 63;
        int q = t >> 10; int k = t & 1023;
        int jh = q ^ 1;
        int fh = jh * 1024 + k; int g = fh >> 11; int m = fh & 2047;
        float sx = Ux[k * 64 + r] * Vx[(q * 1024 + k) * 64 + r];
        float sh = Uh0[k * 64 + r] * Vh0[(g * 64 + r) * 2048 + m];
        #pragma unroll
        for (int d = 32; d > 0; d >>= 1) {
            sx += __shfl_xor(sx, d, 64);
            sh += __shfl_xor(sh, d, 64);
        }
        if (r == 0) {
            cx[t] = dia_x[k] - sx;
            ch[t] = dia_h[k] - sh;
            bb[t] = bias_x[q * 1024 + k] + bias_h[jh * 1024 + k];
        }
    }
}

// ---------------------------------------------------------------------------
// Stage 1 (unchanged): 16-row blocks, grid (512,3).
__global__ __launch_bounds__(256) void s1_kernel(
    const float* __restrict__ x, const float* __restrict__ h,
    const _Float16* __restrict__ U1f, const _Float16* __restrict__ Uh1f,
    _Float16* __restrict__ Ta, _Float16* __restrict__ Tb)
{
    __shared__ __align__(16) _Float16 Ash[16][520];

    const int job = blockIdx.y;
    const int b0 = blockIdx.x * 16;
    const int tid = threadIdx.x;
    const int w = tid >> 6, l = tid & 63, l15 = l & 15, quad = l >> 4;

    f32x4 acc0 = {}, acc1 = {};
    const int nkc = (job == 0) ? 2 : 1;
    const float* src = (job == 0) ? x : h;

    for (int kc = 0; kc < nkc; ++kc) {
        const int koff = (job == 2) ? 512 : kc * 512;
        #pragma unroll
        for (int ii = 0; ii < 8; ++ii) {
            int idx = tid + ii * 256;      // 0..2047
            int row = idx >> 7, c4 = idx & 127;
            float4 f = *(const float4*)&src[(size_t)(b0 + row) * 1024 + koff + c4 * 4];
            half4v p;
            p[0] = (_Float16)f.x; p[1] = (_Float16)f.y;
            p[2] = (_Float16)f.z; p[3] = (_Float16)f.w;
            *(half4v*)&Ash[row][c4 * 4] = p;
        }
        __syncthreads();
        if (job == 0) {
            const _Float16* bp = U1f + ((size_t)(w * 32 + kc * 16) * 64 + l) * 8;
            #pragma unroll
            for (int ks = 0; ks < 16; ++ks) {
                half8 a = *(const half8*)&Ash[l15][ks * 32 + quad * 8];
                half8 b = *(const half8*)(bp + (size_t)ks * 512);
                acc0 = __builtin_amdgcn_mfma_f32_16x16x32_f16(a, b, acc0, 0, 0, 0);
            }
        } else {
            const int j0 = (job == 1) ? 0 : 1;   // -> Ta
            const int j1 = (job == 1) ? 3 : 2;   // -> Tb
            const _Float16* bp0 = Uh1f + ((size_t)((j0 * 4 + w) * 16) * 64 + l) * 8;
            const _Float16* bp1 = Uh1f + ((size_t)((j1 * 4 + w) * 16) * 64 + l) * 8;
            #pragma unroll
            for (int ks = 0; ks < 16; ++ks) {
                half8 a = *(const half8*)&Ash[l15][ks * 32 + quad * 8];
                half8 b0 = *(const half8*)(bp0 + (size_t)ks * 512);
                acc0 = __builtin_amdgcn_mfma_f32_16x16x32_f16(a, b0, acc0, 0, 0, 0);
                half8 b1 = *(const half8*)(bp1 + (size_t)ks * 512);
                acc1 = __builtin_amdgcn_mfma_f32_16x16x32_f16(a, b1, acc1, 0, 0, 0);
            }
        }
        __syncthreads();
    }
    if (job == 0) {
        int col = w * 16 + l15;
        #pragma unroll
        for (int r = 0; r < 4; ++r) {
            int row = b0 + quad * 4 + r;
            _Float16 v = (_Float16)acc0[r];
            Ta[(size_t)row * 192 + col] = v;
            Tb[(size_t)row * 192 + col] = v;
        }
    } else {
        int colA = ((job == 1) ? 64 : 128) + w * 16 + l15;
        int colB = ((job == 1) ? 128 : 64) + w * 16 + l15;
        #pragma unroll
        for (int r = 0; r < 4; ++r) {
            int row = b0 + quad * 4 + r;
            Ta[(size_t)row * 192 + colA] = (_Float16)acc0[r];
            Tb[(size_t)row * 192 + colB] = (_Float16)acc1[r];
        }
    }
}

// ---------------------------------------------------------------------------
// Stage 2 v5: 32 rows x 64 cols per block, grid (256, 16) = 4096 blocks.
// Barrier-free, LDS-free. A-frags straight from global (L2/L3-hot; each
// 1KB wave load = 16 fully-used 64B lines). Each B-frag feeds 2 MFMAs
// (row-tiles rt=0,1). Epilogue x/h/c operands batch-prefetched BEFORE the
// MFMA loop so their HBM latency hides under compute (the old version's
// in-loop scalar loads serialized at VGPR=52).
__global__ __launch_bounds__(256, 4) void s2_kernel(
    const _Float16* __restrict__ Ta, const _Float16* __restrict__ Tb,
    const _Float16* __restrict__ W2f,
    const float* __restrict__ cx, const float* __restrict__ ch,
    const float* __restrict__ bb,
    const float* __restrict__ x, const float* __restrict__ h,
    const float* __restrict__ c, float* __restrict__ out)
{
    const int b0 = blockIdx.x * 32;
    const int tid = threadIdx.x;
    const int w = tid >> 6, l = tid & 63, l15 = l & 15, quad = l >> 4;
    const int ctg = blockIdx.y * 4 + w;    // global col-tile 0..63
    const int k = ctg * 16 + l15;          // this lane's output column

    // ---- batch-issue all epilogue operand loads up front (24 in flight) ----
    const size_t base = (size_t)(b0 + quad * 4) * 1024 + k;
    float xv[2][4], hv[2][4], cv[2][4];
    #pragma unroll
    for (int rt = 0; rt < 2; ++rt) {
        #pragma unroll
        for (int r = 0; r < 4; ++r) {
            size_t off = base + (size_t)(rt * 16 + r) * 1024;
            xv[rt][r] = x[off];
            hv[rt][r] = h[off];
            cv[rt][r] = c[off];
        }
    }
    float cxi = cx[k], cxf = cx[1024 + k], cxo = cx[2048 + k], cxn = cx[3072 + k];
    float chi = ch[k], chf = ch[1024 + k], cho = ch[2048 + k], chn = ch[3072 + k];
    float bbi = bb[k], bbf = bb[1024 + k], bbo = bb[2048 + k], bbn = bb[3072 + k];

    // ---- MFMA main loop ----
    const size_t laneoff = (size_t)l * 8;
    const _Float16* bpi = W2f + (size_t)((0 * 64 + ctg) * 6) * 512 + laneoff;
    const _Float16* bpf = W2f + (size_t)((1 * 64 + ctg) * 6) * 512 + laneoff;
    const _Float16* bpo = W2f + (size_t)((2 * 64 + ctg) * 6) * 512 + laneoff;
    const _Float16* bpn = W2f + (size_t)((3 * 64 + ctg) * 6) * 512 + laneoff;
    const _Float16* aTa = Ta + (size_t)(b0 + l15) * 192 + quad * 8;
    const _Float16* aTb = Tb + (size_t)(b0 + l15) * 192 + quad * 8;

    f32x4 acc[4][2] = {};                  // [sg][row-tile]
    #pragma unroll
    for (int ks = 0; ks < 6; ++ks) {
        half8 bi = *(const half8*)(bpi + (size_t)ks * 512);
        half8 bf = *(const half8*)(bpf + (size_t)ks * 512);
        half8 bo = *(const half8*)(bpo + (size_t)ks * 512);
        half8 bn = *(const half8*)(bpn + (size_t)ks * 512);
        #pragma unroll
        for (int rt = 0; rt < 2; ++rt) {
            half8 aA = *(const half8*)(aTa + (size_t)(rt * 16) * 192 + ks * 32);
            half8 aB = *(const half8*)(aTb + (size_t)(rt * 16) * 192 + ks * 32);
            acc[0][rt] = __builtin_amdgcn_mfma_f32_16x16x32_f16(aA, bi, acc[0][rt], 0, 0, 0);
            acc[1][rt] = __builtin_amdgcn_mfma_f32_16x16x32_f16(aA, bf, acc[1][rt], 0, 0, 0);
            acc[2][rt] = __builtin_amdgcn_mfma_f32_16x16x32_f16(aB, bo, acc[2][rt], 0, 0, 0);
            acc[3][rt] = __builtin_amdgcn_mfma_f32_16x16x32_f16(aB, bn, acc[3][rt], 0, 0, 0);
        }
    }

    // ---- fused elementwise epilogue (D: col=l15 -> k, row=quad*4+r -> batch) ----
    #pragma unroll
    for (int rt = 0; rt < 2; ++rt) {
        #pragma unroll
        for (int r = 0; r < 4; ++r) {
            size_t off = base + (size_t)(rt * 16 + r) * 1024;
            float pi = acc[0][rt][r] + xv[rt][r] * cxi + hv[rt][r] * chi + bbi;
            float pf = acc[1][rt][r] + xv[rt][r] * cxf + hv[rt][r] * chf + bbf;
            float po = acc[2][rt][r] + xv[rt][r] * cxo + hv[rt][r] * cho + bbo;
            float pn = acc[3][rt][r] + xv[rt][r] * cxn + hv[rt][r] * chn + bbn;
            // sigmoid/tanh via fast rcp (tolerance 0.115 >> rcp error)
            float ig = __builtin_amdgcn_rcpf(1.f + __expf(-pi));
            float fg = __builtin_amdgcn_rcpf(1.f + __expf(-pf));
            float og = __builtin_amdgcn_rcpf(1.f + __expf(-po));
            float ng = 1.f - 2.f * __builtin_amdgcn_rcpf(__expf(2.f * pn) + 1.f);
            float cn = fg * cv[rt][r] + ig * ng;
            float tc = 1.f - 2.f * __builtin_amdgcn_rcpf(__expf(2.f * cn) + 1.f);
            out[off] = og * tc;
            out[(size_t)8388608 + off] = cn;
        }
    }
}

// ---------------------------------------------------------------------------
extern "C" void kernel_launch(void* const* d_in, const int* in_sizes, int n_in,
                              void* d_out, int out_size, void* d_ws, size_t ws_size,
                              hipStream_t stream)
{
    const float* x      = (const float*)d_in[0];
    const float* h      = (const float*)d_in[1];
    const float* c      = (const float*)d_in[2];
    const float* dia_x  = (const float*)d_in[3];
    const float* dia_h  = (const float*)d_in[4];
    const float* Ux     = (const float*)d_in[5];
    const float* Vx     = (const float*)d_in[6];
    const float* Uh0    = (const float*)d_in[7];
    const float* Vh0    = (const float*)d_in[8];
    const float* Uh1    = (const float*)d_in[9];
    const float* Vh1    = (const float*)d_in[10];
    const float* bias_x = (const float*)d_in[11];
    const float* bias_h = (const float*)d_in[12];
    float* out = (float*)d_out;

    char* ws = (char*)d_ws;
    _Float16* TaW  = (_Float16*)(ws + WS_TA);
    _Float16* TbW  = (_Float16*)(ws + WS_TB);
    _Float16* U1f  = (_Float16*)(ws + WS_U1F);
    _Float16* Uh1f = (_Float16*)(ws + WS_UH1F);
    _Float16* W2f  = (_Float16*)(ws + WS_W2);
    float* cx = (float*)(ws + WS_CX);
    float* ch = (float*)(ws + WS_CH);
    float* bb = (float*)(ws + WS_BB);

    // 8192 + 16384 + 98304 + 262144 = 385024 threads = 1504 blocks
    prep_kernel<<<1504, 256, 0, stream>>>(Ux, Vx, Uh0, Vh0, Uh1, Vh1,
                                          dia_x, dia_h, bias_x, bias_h,
                                          U1f, Uh1f, W2f, cx, ch, bb);
    s1_kernel<<<dim3(512, 3), 256, 0, stream>>>(x, h, U1f, Uh1f, TaW, TbW);
    s2_kernel<<<dim3(256, 16), 256, 0, stream>>>(TaW, TbW, W2f, cx, ch, bb,
                                                 x, h, c, out);
}

// Round 3
// 246.481 us; speedup vs baseline: 1.0451x; 1.0451x over previous
//
#include <hip/hip_runtime.h>

// ---------------------------------------------------------------------------
// VM-LSTM cell, B=8192, D=H=1024, G=2, WR=64, URANKS=[64,64]
//
//   prep  : stage-1 weights MFMA-frag-major fp16 (U1f, Uh1f); stage-2 W2f
//           frag-major fp16; correction vectors cx/ch/bb (wave-parallel).
//   fused : s1+s2 in ONE kernel. 32 rows/block, 512 thr (8 waves), grid 256
//           = 1 block/CU (LDS-capped: 153 KB).
//           Phase A: stage x,h -> fp16 LDS (256 KB HBM burst, full MLP).
//           Phase B: stage-1 MFMAs -> T=[X|P0|P1|P2|P3] (32x320) in LDS.
//             wave w: X-tile (rt=w&1, ct=w>>1, K=1024) + 4 P-tiles (K=512).
//           Phase C: barrier-free stage-2: 24 A-frags hoisted to registers
//             (T is column-tile-invariant!), 8 col-tiles/wave, B-frags from
//             W2f (L2-hot), c prefetched 1 tile ahead, epilogue corrections
//             read fp16 x/h from LDS (err ~5e-4 << tol), nontemporal out
//             stores (protect W2f L2 residency).
//           Eliminates Ta/Tb HBM round-trip and the 2nd x/h read.
// Gates: q=0 i, 1 f (secIF); 2 o, 3 n (secON). W2f layout unchanged.
// ---------------------------------------------------------------------------

typedef _Float16 half8 __attribute__((ext_vector_type(8)));
typedef _Float16 half4v __attribute__((ext_vector_type(4)));
typedef float f32x4 __attribute__((ext_vector_type(4)));

// workspace offsets (bytes) — Ta/Tb eliminated
#define WS_U1F   0                     // 131072 B
#define WS_UH1F  131072                // 262144 B
#define WS_W2    393216                // 1572864 B (frag-major)
#define WS_CX    1966080               // 4096 fp32
#define WS_CH    1982464
#define WS_BB    1998848

// ---------------------------------------------------------------------------
__global__ __launch_bounds__(256) void prep_kernel(
    const float* __restrict__ Ux, const float* __restrict__ Vx,
    const float* __restrict__ Uh0, const float* __restrict__ Vh0,
    const float* __restrict__ Uh1, const float* __restrict__ Vh1,
    const float* __restrict__ dia_x, const float* __restrict__ dia_h,
    const float* __restrict__ bias_x, const float* __restrict__ bias_h,
    _Float16* __restrict__ U1f, _Float16* __restrict__ Uh1f,
    _Float16* __restrict__ W2f, float* __restrict__ cx,
    float* __restrict__ ch, float* __restrict__ bb)
{
    int e = blockIdx.x * 256 + threadIdx.x;
    if (e < 8192) {
        // U1f[ct(4)][ks(32)][lane][8]: B-frag for x@Ux.
        int lane = e & 63, ks = (e >> 6) & 31, ct = e >> 11;
        int l15 = lane & 15, quad = lane >> 4;
        half8 v8;
        #pragma unroll
        for (int jj = 0; jj < 8; ++jj) {
            int k = ks * 32 + quad * 8 + jj;
            v8[jj] = (_Float16)Ux[k * 64 + ct * 16 + l15];
        }
        *(half8*)&U1f[(size_t)e * 8] = v8;
    } else if (e < 24576) {
        // Uh1f[j(4)][ct(4)][ks(16)][lane][8]; j: 0=Uh0g0,1=Uh1g0,2=Uh0g1,3=Uh1g1
        int t = e - 8192;
        int lane = t & 63, ks = (t >> 6) & 15, ct = (t >> 10) & 3, j = t >> 12;
        int l15 = lane & 15, quad = lane >> 4;
        const float* src = (j & 1) ? Uh1 : Uh0;
        int g = j >> 1;
        half8 v8;
        #pragma unroll
        for (int jj = 0; jj < 8; ++jj) {
            int k = ks * 32 + quad * 8 + jj;
            v8[jj] = (_Float16)src[(g * 512 + k) * 64 + ct * 16 + l15];
        }
        *(half8*)&Uh1f[(size_t)t * 8] = v8;
    } else if (e < 122880) {
        // W2f fragment-major: t = (((s*2+g01)*64 + ct)*6 + ks)*64 + lane
        int t = e - 24576;                 // 0..98303
        int lane = t & 63;
        int ksq  = (t >> 6) % 6;
        int ct   = (t / 384) & 63;
        int g01  = (t / 24576) & 1;
        int s    = t / 49152;
        int l15 = lane & 15, quad = lane >> 4;
        int k = ct * 16 + l15;             // output column
        int jx = s * 2 + g01;
        int m = (g01 == 0) ? (1024 + k) : k;
        half8 v8;
        #pragma unroll
        for (int jj = 0; jj < 8; ++jj) {
            int kk = ksq * 32 + quad * 8 + jj;   // K index 0..191
            int r = kk & 63, sect = kk >> 6;
            float val;
            if (sect == 0)      val = Vx[(jx * 1024 + k) * 64 + r];
            else if (sect == 1) val = Vh0[(s * 64 + r) * 2048 + m];
            else                val = Vh1[(s * 64 + r) * 2048 + m];
            v8[jj] = (_Float16)val;
        }
        *(half8*)&W2f[(size_t)t * 8] = v8;
    } else {
        // correction vectors, wave-parallel: one wave per element t, lane = r.
        int t64 = e - 122880;              // 0..262143
        int t = t64 >> 6;                  // 0..4095
        int r = t64 & 63;
        int q = t >> 10; int k = t & 1023;
        int jh = q ^ 1;
        int fh = jh * 1024 + k; int g = fh >> 11; int m = fh & 2047;
        float sx = Ux[k * 64 + r] * Vx[(q * 1024 + k) * 64 + r];
        float sh = Uh0[k * 64 + r] * Vh0[(g * 64 + r) * 2048 + m];
        #pragma unroll
        for (int d = 32; d > 0; d >>= 1) {
            sx += __shfl_xor(sx, d, 64);
            sh += __shfl_xor(sh, d, 64);
        }
        if (r == 0) {
            cx[t] = dia_x[k] - sx;
            ch[t] = dia_h[k] - sh;
            bb[t] = bias_x[q * 1024 + k] + bias_h[jh * 1024 + k];
        }
    }
}

// ---------------------------------------------------------------------------
__global__ __launch_bounds__(512, 2) void fused_kernel(
    const float* __restrict__ x, const float* __restrict__ h,
    const float* __restrict__ c,
    const _Float16* __restrict__ U1f, const _Float16* __restrict__ Uh1f,
    const _Float16* __restrict__ W2f,
    const float* __restrict__ cx, const float* __restrict__ ch,
    const float* __restrict__ bb, float* __restrict__ out)
{
    // pad rows by +8 fp16 (16B): keeps half8 alignment, breaks pow2 stride
    __shared__ __align__(16) _Float16 Xsh[32][1032];   // 66048 B
    __shared__ __align__(16) _Float16 Hsh[32][1032];   // 66048 B
    __shared__ __align__(16) _Float16 Tsh[32][328];    // 20992 B  (total 153088)

    const int tid = threadIdx.x;
    const int w = tid >> 6, l = tid & 63, l15 = l & 15, quad = l >> 4;
    const int b0 = blockIdx.x * 32;
    const size_t rowbase = (size_t)b0 * 1024;

    // ---- Phase A: stage x,h -> fp16 LDS (32 rows x 1024 each) ----
    {
        const float* xs = x + rowbase;
        const float* hs = h + rowbase;
        #pragma unroll
        for (int ii = 0; ii < 16; ++ii) {
            int idx = tid + ii * 512;          // 0..8191 = 32 rows x 256 float4
            int row = idx >> 8, c4 = idx & 255;
            float4 fx = *(const float4*)&xs[(size_t)row * 1024 + c4 * 4];
            float4 fh = *(const float4*)&hs[(size_t)row * 1024 + c4 * 4];
            half4v px, ph;
            px[0] = (_Float16)fx.x; px[1] = (_Float16)fx.y;
            px[2] = (_Float16)fx.z; px[3] = (_Float16)fx.w;
            ph[0] = (_Float16)fh.x; ph[1] = (_Float16)fh.y;
            ph[2] = (_Float16)fh.z; ph[3] = (_Float16)fh.w;
            *(half4v*)&Xsh[row][c4 * 4] = px;
            *(half4v*)&Hsh[row][c4 * 4] = ph;
        }
    }
    __syncthreads();

    // ---- Phase B: stage-1 -> Tsh = [X(0) | P0(64) | P1(128) | P2(192) | P3(256)]
    {
        // X-tile: out cols ct*16.., rows rt*16.., K=1024 over Xsh
        int rt = w & 1, ct = w >> 1;
        f32x4 acc = {};
        const _Float16* bp = U1f + ((size_t)(ct * 32) * 64 + l) * 8;
        #pragma unroll
        for (int ks = 0; ks < 32; ++ks) {
            half8 a = *(const half8*)&Xsh[rt * 16 + l15][ks * 32 + quad * 8];
            half8 b = *(const half8*)(bp + (size_t)ks * 512);
            acc = __builtin_amdgcn_mfma_f32_16x16x32_f16(a, b, acc, 0, 0, 0);
        }
        #pragma unroll
        for (int r = 0; r < 4; ++r)
            Tsh[rt * 16 + quad * 4 + r][ct * 16 + l15] = (_Float16)acc[r];

        // P-tiles: 4 per wave; p = w*4+i -> j = p>>3, rt=(p&7)>>2, ct=p&3
        // A = Hsh half: j in {0,3} -> cols 0-511; j in {1,2} -> cols 512-1023
        #pragma unroll
        for (int i = 0; i < 4; ++i) {
            int p = w * 4 + i;
            int j = p >> 3, rem = p & 7, prt = rem >> 2, pct = rem & 3;
            int hoff = (j == 1 || j == 2) ? 512 : 0;
            f32x4 pa = {};
            const _Float16* pb = Uh1f + ((size_t)((j * 4 + pct) * 16) * 64 + l) * 8;
            #pragma unroll
            for (int ks = 0; ks < 16; ++ks) {
                half8 a = *(const half8*)&Hsh[prt * 16 + l15][hoff + ks * 32 + quad * 8];
                half8 b = *(const half8*)(pb + (size_t)ks * 512);
                pa = __builtin_amdgcn_mfma_f32_16x16x32_f16(a, b, pa, 0, 0, 0);
            }
            #pragma unroll
            for (int r = 0; r < 4; ++r)
                Tsh[prt * 16 + quad * 4 + r][64 + j * 64 + pct * 16 + l15] = (_Float16)pa[r];
        }
    }
    __syncthreads();

    // ---- Phase C: stage-2, barrier-free. A-frags are col-tile-invariant:
    //      hoist all 24 (2 pairs x 6 ks x 2 rt) into registers once.
    const int secIF[3] = {0, 64, 128};     // gates i,f  = [X | P0 | P1]
    const int secON[3] = {0, 192, 256};    // gates o,n  = [X | P2 | P3]
    half8 Afrag[2][6][2];                  // [pair][ks][rt]
    #pragma unroll
    for (int ks = 0; ks < 6; ++ks) {
        #pragma unroll
        for (int rt = 0; rt < 2; ++rt) {
            int coff = (ks & 1) * 32 + quad * 8;
            Afrag[0][ks][rt] = *(const half8*)&Tsh[rt * 16 + l15][secIF[ks >> 1] + coff];
            Afrag[1][ks][rt] = *(const half8*)&Tsh[rt * 16 + l15][secON[ks >> 1] + coff];
        }
    }

    // c prefetch double-buffer (static indices after full unroll)
    float cpref[2][2][4];
    {
        int k0 = w * 16 + l15;             // tile i=0: ctg = w
        #pragma unroll
        for (int rt = 0; rt < 2; ++rt)
            #pragma unroll
            for (int r = 0; r < 4; ++r)
                cpref[0][rt][r] = c[rowbase + (size_t)(rt * 16 + quad * 4 + r) * 1024 + k0];
    }

    #pragma unroll
    for (int i = 0; i < 8; ++i) {
        const int ctg = w + 8 * i;         // col-tile 0..63, disjoint across waves
        const int k = ctg * 16 + l15;

        // prefetch c for next tile
        if (i < 7) {
            int kn = (ctg + 8) * 16 + l15;
            #pragma unroll
            for (int rt = 0; rt < 2; ++rt)
                #pragma unroll
                for (int r = 0; r < 4; ++r)
                    cpref[(i + 1) & 1][rt][r] =
                        c[rowbase + (size_t)(rt * 16 + quad * 4 + r) * 1024 + kn];
        }

        // correction scalars (L2-hot, issued before MFMA loop)
        float cxi = cx[k], cxf = cx[1024 + k], cxo = cx[2048 + k], cxn = cx[3072 + k];
        float chi = ch[k], chf = ch[1024 + k], cho = ch[2048 + k], chn = ch[3072 + k];
        float bbi = bb[k], bbf = bb[1024 + k], bbo = bb[2048 + k], bbn = bb[3072 + k];

        const size_t laneoff = (size_t)l * 8;
        const _Float16* bpi = W2f + (size_t)((0 * 64 + ctg) * 6) * 512 + laneoff;
        const _Float16* bpf = W2f + (size_t)((1 * 64 + ctg) * 6) * 512 + laneoff;
        const _Float16* bpo = W2f + (size_t)((2 * 64 + ctg) * 6) * 512 + laneoff;
        const _Float16* bpn = W2f + (size_t)((3 * 64 + ctg) * 6) * 512 + laneoff;

        f32x4 acc[4][2] = {};              // [gate][rt]
        #pragma unroll
        for (int ks = 0; ks < 6; ++ks) {
            half8 bi = *(const half8*)(bpi + (size_t)ks * 512);
            half8 bf = *(const half8*)(bpf + (size_t)ks * 512);
            half8 bo = *(const half8*)(bpo + (size_t)ks * 512);
            half8 bn = *(const half8*)(bpn + (size_t)ks * 512);
            #pragma unroll
            for (int rt = 0; rt < 2; ++rt) {
                acc[0][rt] = __builtin_amdgcn_mfma_f32_16x16x32_f16(Afrag[0][ks][rt], bi, acc[0][rt], 0, 0, 0);
                acc[1][rt] = __builtin_amdgcn_mfma_f32_16x16x32_f16(Afrag[0][ks][rt], bf, acc[1][rt], 0, 0, 0);
                acc[2][rt] = __builtin_amdgcn_mfma_f32_16x16x32_f16(Afrag[1][ks][rt], bo, acc[2][rt], 0, 0, 0);
                acc[3][rt] = __builtin_amdgcn_mfma_f32_16x16x32_f16(Afrag[1][ks][rt], bn, acc[3][rt], 0, 0, 0);
            }
        }

        // epilogue: corrections from fp16 LDS x/h; c from prefetch regs
        #pragma unroll
        for (int rt = 0; rt < 2; ++rt) {
            #pragma unroll
            for (int r = 0; r < 4; ++r) {
                int rl = rt * 16 + quad * 4 + r;
                size_t off = rowbase + (size_t)rl * 1024 + k;
                float xv = (float)Xsh[rl][k];
                float hv = (float)Hsh[rl][k];
                float cvv = cpref[i & 1][rt][r];
                float pi = acc[0][rt][r] + xv * cxi + hv * chi + bbi;
                float pf = acc[1][rt][r] + xv * cxf + hv * chf + bbf;
                float po = acc[2][rt][r] + xv * cxo + hv * cho + bbo;
                float pn = acc[3][rt][r] + xv * cxn + hv * chn + bbn;
                float ig = __builtin_amdgcn_rcpf(1.f + __expf(-pi));
                float fg = __builtin_amdgcn_rcpf(1.f + __expf(-pf));
                float og = __builtin_amdgcn_rcpf(1.f + __expf(-po));
                float ng = 1.f - 2.f * __builtin_amdgcn_rcpf(__expf(2.f * pn) + 1.f);
                float cn = fg * cvv + ig * ng;
                float tc = 1.f - 2.f * __builtin_amdgcn_rcpf(__expf(2.f * cn) + 1.f);
                __builtin_nontemporal_store(og * tc, &out[off]);
                __builtin_nontemporal_store(cn, &out[(size_t)8388608 + off]);
            }
        }
    }
}

// ---------------------------------------------------------------------------
extern "C" void kernel_launch(void* const* d_in, const int* in_sizes, int n_in,
                              void* d_out, int out_size, void* d_ws, size_t ws_size,
                              hipStream_t stream)
{
    const float* x      = (const float*)d_in[0];
    const float* h      = (const float*)d_in[1];
    const float* c      = (const float*)d_in[2];
    const float* dia_x  = (const float*)d_in[3];
    const float* dia_h  = (const float*)d_in[4];
    const float* Ux     = (const float*)d_in[5];
    const float* Vx     = (const float*)d_in[6];
    const float* Uh0    = (const float*)d_in[7];
    const float* Vh0    = (const float*)d_in[8];
    const float* Uh1    = (const float*)d_in[9];
    const float* Vh1    = (const float*)d_in[10];
    const float* bias_x = (const float*)d_in[11];
    const float* bias_h = (const float*)d_in[12];
    float* out = (float*)d_out;

    char* ws = (char*)d_ws;
    _Float16* U1f  = (_Float16*)(ws + WS_U1F);
    _Float16* Uh1f = (_Float16*)(ws + WS_UH1F);
    _Float16* W2f  = (_Float16*)(ws + WS_W2);
    float* cx = (float*)(ws + WS_CX);
    float* ch = (float*)(ws + WS_CH);
    float* bb = (float*)(ws + WS_BB);

    // 8192 + 16384 + 98304 + 262144 = 385024 threads = 1504 blocks
    prep_kernel<<<1504, 256, 0, stream>>>(Ux, Vx, Uh0, Vh0, Uh1, Vh1,
                                          dia_x, dia_h, bias_x, bias_h,
                                          U1f, Uh1f, W2f, cx, ch, bb);
    fused_kernel<<<256, 512, 0, stream>>>(x, h, c, U1f, Uh1f, W2f,
                                          cx, ch, bb, out);
}

// Round 5
// 203.178 us; speedup vs baseline: 1.2678x; 1.2131x over previous
//
#include <hip/hip_runtime.h>

// ---------------------------------------------------------------------------
// VM-LSTM cell, B=8192, D=H=1024, G=2, WR=64, URANKS=[64,64]
//
//   prep  : stage-1 weights MFMA-frag-major fp16 (U1f, Uh1f); stage-2 W2f
//           frag-major fp16; correction vectors cx/ch/bb (wave-parallel).
//   fused : s1+s2 in ONE kernel. 32 rows/block, 1024 thr (16 waves), grid
//           256 = 1 block/CU (LDS-capped: 153 KB), 4 waves/SIMD.
//           Phase A: stage x,h -> fp16 LDS (nontemporal loads: single-use
//             streams, protect W2f L2 residency). NOTE: nontemporal builtin
//             needs ext_vector types, NOT HIP_vector_type (r4 compile fail).
//           Phase B: stage-1 MFMAs -> T=[X|P0|P1|P2|P3] (32x320) in LDS.
//             waves 0-7: X-tile + P-tile w (48 MFMA); waves 8-15: 3 P-tiles
//             (48 MFMA) — balanced.
//           Phase C: barrier-free stage-2: 4 col-tiles/wave; A-frags from
//             LDS in-loop (NOT register-hoisted — that cost 96 VGPRs and
//             serialized the B loads); B-frags from W2f (L2-hot, 24 loads
//             batched in flight); c prefetched 1 tile ahead (nontemporal);
//             PLAIN out stores (nt stores write-amplified 2x: 125 vs 66 MB).
// Gates: q=0 i, 1 f (secIF); 2 o, 3 n (secON). W2f layout unchanged.
// ---------------------------------------------------------------------------

typedef _Float16 half8 __attribute__((ext_vector_type(8)));
typedef _Float16 half4v __attribute__((ext_vector_type(4)));
typedef float f32x4 __attribute__((ext_vector_type(4)));

// workspace offsets (bytes)
#define WS_U1F   0                     // 131072 B
#define WS_UH1F  131072                // 262144 B
#define WS_W2    393216                // 1572864 B (frag-major)
#define WS_CX    1966080               // 4096 fp32
#define WS_CH    1982464
#define WS_BB    1998848

// ---------------------------------------------------------------------------
__global__ __launch_bounds__(256) void prep_kernel(
    const float* __restrict__ Ux, const float* __restrict__ Vx,
    const float* __restrict__ Uh0, const float* __restrict__ Vh0,
    const float* __restrict__ Uh1, const float* __restrict__ Vh1,
    const float* __restrict__ dia_x, const float* __restrict__ dia_h,
    const float* __restrict__ bias_x, const float* __restrict__ bias_h,
    _Float16* __restrict__ U1f, _Float16* __restrict__ Uh1f,
    _Float16* __restrict__ W2f, float* __restrict__ cx,
    float* __restrict__ ch, float* __restrict__ bb)
{
    int e = blockIdx.x * 256 + threadIdx.x;
    if (e < 8192) {
        // U1f[ct(4)][ks(32)][lane][8]: B-frag for x@Ux.
        int lane = e & 63, ks = (e >> 6) & 31, ct = e >> 11;
        int l15 = lane & 15, quad = lane >> 4;
        half8 v8;
        #pragma unroll
        for (int jj = 0; jj < 8; ++jj) {
            int k = ks * 32 + quad * 8 + jj;
            v8[jj] = (_Float16)Ux[k * 64 + ct * 16 + l15];
        }
        *(half8*)&U1f[(size_t)e * 8] = v8;
    } else if (e < 24576) {
        // Uh1f[j(4)][ct(4)][ks(16)][lane][8]; j: 0=Uh0g0,1=Uh1g0,2=Uh0g1,3=Uh1g1
        int t = e - 8192;
        int lane = t & 63, ks = (t >> 6) & 15, ct = (t >> 10) & 3, j = t >> 12;
        int l15 = lane & 15, quad = lane >> 4;
        const float* src = (j & 1) ? Uh1 : Uh0;
        int g = j >> 1;
        half8 v8;
        #pragma unroll
        for (int jj = 0; jj < 8; ++jj) {
            int k = ks * 32 + quad * 8 + jj;
            v8[jj] = (_Float16)src[(g * 512 + k) * 64 + ct * 16 + l15];
        }
        *(half8*)&Uh1f[(size_t)t * 8] = v8;
    } else if (e < 122880) {
        // W2f fragment-major: t = (((s*2+g01)*64 + ct)*6 + ks)*64 + lane
        int t = e - 24576;                 // 0..98303
        int lane = t & 63;
        int ksq  = (t >> 6) % 6;
        int ct   = (t / 384) & 63;
        int g01  = (t / 24576) & 1;
        int s    = t / 49152;
        int l15 = lane & 15, quad = lane >> 4;
        int k = ct * 16 + l15;             // output column
        int jx = s * 2 + g01;
        int m = (g01 == 0) ? (1024 + k) : k;
        half8 v8;
        #pragma unroll
        for (int jj = 0; jj < 8; ++jj) {
            int kk = ksq * 32 + quad * 8 + jj;   // K index 0..191
            int r = kk & 63, sect = kk >> 6;
            float val;
            if (sect == 0)      val = Vx[(jx * 1024 + k) * 64 + r];
            else if (sect == 1) val = Vh0[(s * 64 + r) * 2048 + m];
            else                val = Vh1[(s * 64 + r) * 2048 + m];
            v8[jj] = (_Float16)val;
        }
        *(half8*)&W2f[(size_t)t * 8] = v8;
    } else {
        // correction vectors, wave-parallel: one wave per element t, lane = r.
        int t64 = e - 122880;              // 0..262143
        int t = t64 >> 6;                  // 0..4095
        int r = t64 & 63;
        int q = t >> 10; int k = t & 1023;
        int jh = q ^ 1;
        int fh = jh * 1024 + k; int g = fh >> 11; int m = fh & 2047;
        float sx = Ux[k * 64 + r] * Vx[(q * 1024 + k) * 64 + r];
        float sh = Uh0[k * 64 + r] * Vh0[(g * 64 + r) * 2048 + m];
        #pragma unroll
        for (int d = 32; d > 0; d >>= 1) {
            sx += __shfl_xor(sx, d, 64);
            sh += __shfl_xor(sh, d, 64);
        }
        if (r == 0) {
            cx[t] = dia_x[k] - sx;
            ch[t] = dia_h[k] - sh;
            bb[t] = bias_x[q * 1024 + k] + bias_h[jh * 1024 + k];
        }
    }
}

// ---------------------------------------------------------------------------
__global__ __launch_bounds__(1024) void fused_kernel(
    const float* __restrict__ x, const float* __restrict__ h,
    const float* __restrict__ c,
    const _Float16* __restrict__ U1f, const _Float16* __restrict__ Uh1f,
    const _Float16* __restrict__ W2f,
    const float* __restrict__ cx, const float* __restrict__ ch,
    const float* __restrict__ bb, float* __restrict__ out)
{
    // pad rows by +8 fp16 (16B): keeps half8 alignment, breaks pow2 stride
    __shared__ __align__(16) _Float16 Xsh[32][1032];   // 66048 B
    __shared__ __align__(16) _Float16 Hsh[32][1032];   // 66048 B
    __shared__ __align__(16) _Float16 Tsh[32][328];    // 20992 B  (total 153088)

    const int tid = threadIdx.x;
    const int w = tid >> 6, l = tid & 63, l15 = l & 15, quad = l >> 4;
    const int b0 = blockIdx.x * 32;
    const size_t rowbase = (size_t)b0 * 1024;

    // ---- Phase A: stage x,h -> fp16 LDS (32 rows x 1024 each) ----
    {
        const float* xs = x + rowbase;
        const float* hs = h + rowbase;
        #pragma unroll
        for (int ii = 0; ii < 8; ++ii) {
            int idx = tid + ii * 1024;         // 0..8191 = 32 rows x 256 float4
            int row = idx >> 8, c4 = idx & 255;
            f32x4 fx = __builtin_nontemporal_load(
                (const f32x4*)&xs[(size_t)row * 1024 + c4 * 4]);
            f32x4 fh = __builtin_nontemporal_load(
                (const f32x4*)&hs[(size_t)row * 1024 + c4 * 4]);
            half4v px, ph;
            px[0] = (_Float16)fx[0]; px[1] = (_Float16)fx[1];
            px[2] = (_Float16)fx[2]; px[3] = (_Float16)fx[3];
            ph[0] = (_Float16)fh[0]; ph[1] = (_Float16)fh[1];
            ph[2] = (_Float16)fh[2]; ph[3] = (_Float16)fh[3];
            *(half4v*)&Xsh[row][c4 * 4] = px;
            *(half4v*)&Hsh[row][c4 * 4] = ph;
        }
    }
    __syncthreads();

    // ---- Phase B: stage-1 -> Tsh = [X(0) | P0(64) | P1(128) | P2(192) | P3(256)]
    if (w < 8) {
        // X-tile: out cols ct*16.., rows rt*16.., K=1024 over Xsh
        int rt = w & 1, ct = w >> 1;
        f32x4 acc = {};
        const _Float16* bp = U1f + ((size_t)(ct * 32) * 64 + l) * 8;
        #pragma unroll
        for (int ks = 0; ks < 32; ++ks) {
            half8 a = *(const half8*)&Xsh[rt * 16 + l15][ks * 32 + quad * 8];
            half8 b = *(const half8*)(bp + (size_t)ks * 512);
            acc = __builtin_amdgcn_mfma_f32_16x16x32_f16(a, b, acc, 0, 0, 0);
        }
        #pragma unroll
        for (int r = 0; r < 4; ++r)
            Tsh[rt * 16 + quad * 4 + r][ct * 16 + l15] = (_Float16)acc[r];
    }
    {
        // P-tiles: p = j*8 + prt*4 + pct, j = which h-matrix, 32 total.
        // waves 0-7: 1 tile (p=w, all j=0); waves 8-15: 3 tiles (p=8..31).
        // A = Hsh half: j in {0,3} -> cols 0-511; j in {1,2} -> cols 512-1023
        int pstart = (w < 8) ? w : 8 + (w - 8) * 3;
        int pcnt   = (w < 8) ? 1 : 3;
        for (int ii = 0; ii < 3; ++ii) {
            if (ii >= pcnt) break;
            int p = pstart + ii;
            int j = p >> 3, rem = p & 7, prt = rem >> 2, pct = rem & 3;
            int hoff = (j == 1 || j == 2) ? 512 : 0;
            f32x4 pa = {};
            const _Float16* pb = Uh1f + ((size_t)((j * 4 + pct) * 16) * 64 + l) * 8;
            #pragma unroll
            for (int ks = 0; ks < 16; ++ks) {
                half8 a = *(const half8*)&Hsh[prt * 16 + l15][hoff + ks * 32 + quad * 8];
                half8 b = *(const half8*)(pb + (size_t)ks * 512);
                pa = __builtin_amdgcn_mfma_f32_16x16x32_f16(a, b, pa, 0, 0, 0);
            }
            #pragma unroll
            for (int r = 0; r < 4; ++r)
                Tsh[prt * 16 + quad * 4 + r][64 + j * 64 + pct * 16 + l15] = (_Float16)pa[r];
        }
    }
    __syncthreads();

    // ---- Phase C: stage-2, barrier-free. 4 col-tiles per wave; A-frags
    //      from LDS in-loop; B-frags from W2f with loads batched in flight.
    const int secIF[3] = {0, 64, 128};     // gates i,f  = [X | P0 | P1]
    const int secON[3] = {0, 192, 256};    // gates o,n  = [X | P2 | P3]

    // c prefetch double-buffer (static indices after full unroll)
    float cpref[2][2][4];
    {
        int k0 = w * 16 + l15;             // tile i=0: ctg = w
        #pragma unroll
        for (int rt = 0; rt < 2; ++rt)
            #pragma unroll
            for (int r = 0; r < 4; ++r)
                cpref[0][rt][r] = __builtin_nontemporal_load(
                    &c[rowbase + (size_t)(rt * 16 + quad * 4 + r) * 1024 + k0]);
    }

    #pragma unroll
    for (int i = 0; i < 4; ++i) {
        const int ctg = w + 16 * i;        // col-tile 0..63, disjoint across waves
        const int k = ctg * 16 + l15;

        // prefetch c for next tile
        if (i < 3) {
            int kn = k + 256;
            #pragma unroll
            for (int rt = 0; rt < 2; ++rt)
                #pragma unroll
                for (int r = 0; r < 4; ++r)
                    cpref[(i + 1) & 1][rt][r] = __builtin_nontemporal_load(
                        &c[rowbase + (size_t)(rt * 16 + quad * 4 + r) * 1024 + kn]);
        }

        // correction scalars (L2-hot, issued before MFMA loop)
        float cxi = cx[k], cxf = cx[1024 + k], cxo = cx[2048 + k], cxn = cx[3072 + k];
        float chi = ch[k], chf = ch[1024 + k], cho = ch[2048 + k], chn = ch[3072 + k];
        float bbi = bb[k], bbf = bb[1024 + k], bbo = bb[2048 + k], bbn = bb[3072 + k];

        const size_t laneoff = (size_t)l * 8;
        const _Float16* bpi = W2f + (size_t)((0 * 64 + ctg) * 6) * 512 + laneoff;
        const _Float16* bpf = W2f + (size_t)((1 * 64 + ctg) * 6) * 512 + laneoff;
        const _Float16* bpo = W2f + (size_t)((2 * 64 + ctg) * 6) * 512 + laneoff;
        const _Float16* bpn = W2f + (size_t)((3 * 64 + ctg) * 6) * 512 + laneoff;

        f32x4 acc[4][2] = {};              // [gate][rt]
        #pragma unroll
        for (int ks = 0; ks < 6; ++ks) {
            half8 bi = *(const half8*)(bpi + (size_t)ks * 512);
            half8 bf = *(const half8*)(bpf + (size_t)ks * 512);
            half8 bo = *(const half8*)(bpo + (size_t)ks * 512);
            half8 bn = *(const half8*)(bpn + (size_t)ks * 512);
            int coff = (ks & 1) * 32 + quad * 8;
            #pragma unroll
            for (int rt = 0; rt < 2; ++rt) {
                half8 aA = *(const half8*)&Tsh[rt * 16 + l15][secIF[ks >> 1] + coff];
                half8 aB = *(const half8*)&Tsh[rt * 16 + l15][secON[ks >> 1] + coff];
                acc[0][rt] = __builtin_amdgcn_mfma_f32_16x16x32_f16(aA, bi, acc[0][rt], 0, 0, 0);
                acc[1][rt] = __builtin_amdgcn_mfma_f32_16x16x32_f16(aA, bf, acc[1][rt], 0, 0, 0);
                acc[2][rt] = __builtin_amdgcn_mfma_f32_16x16x32_f16(aB, bo, acc[2][rt], 0, 0, 0);
                acc[3][rt] = __builtin_amdgcn_mfma_f32_16x16x32_f16(aB, bn, acc[3][rt], 0, 0, 0);
            }
        }

        // epilogue: corrections from fp16 LDS x/h; c from prefetch regs
        #pragma unroll
        for (int rt = 0; rt < 2; ++rt) {
            #pragma unroll
            for (int r = 0; r < 4; ++r) {
                int rl = rt * 16 + quad * 4 + r;
                size_t off = rowbase + (size_t)rl * 1024 + k;
                float xv = (float)Xsh[rl][k];
                float hv = (float)Hsh[rl][k];
                float cvv = cpref[i & 1][rt][r];
                float pi = acc[0][rt][r] + xv * cxi + hv * chi + bbi;
                float pf = acc[1][rt][r] + xv * cxf + hv * chf + bbf;
                float po = acc[2][rt][r] + xv * cxo + hv * cho + bbo;
                float pn = acc[3][rt][r] + xv * cxn + hv * chn + bbn;
                float ig = __builtin_amdgcn_rcpf(1.f + __expf(-pi));
                float fg = __builtin_amdgcn_rcpf(1.f + __expf(-pf));
                float og = __builtin_amdgcn_rcpf(1.f + __expf(-po));
                float ng = 1.f - 2.f * __builtin_amdgcn_rcpf(__expf(2.f * pn) + 1.f);
                float cn = fg * cvv + ig * ng;
                float tc = 1.f - 2.f * __builtin_amdgcn_rcpf(__expf(2.f * cn) + 1.f);
                out[off] = og * tc;
                out[(size_t)8388608 + off] = cn;
            }
        }
    }
}

// ---------------------------------------------------------------------------
extern "C" void kernel_launch(void* const* d_in, const int* in_sizes, int n_in,
                              void* d_out, int out_size, void* d_ws, size_t ws_size,
                              hipStream_t stream)
{
    const float* x      = (const float*)d_in[0];
    const float* h      = (const float*)d_in[1];
    const float* c      = (const float*)d_in[2];
    const float* dia_x  = (const float*)d_in[3];
    const float* dia_h  = (const float*)d_in[4];
    const float* Ux     = (const float*)d_in[5];
    const float* Vx     = (const float*)d_in[6];
    const float* Uh0    = (const float*)d_in[7];
    const float* Vh0    = (const float*)d_in[8];
    const float* Uh1    = (const float*)d_in[9];
    const float* Vh1    = (const float*)d_in[10];
    const float* bias_x = (const float*)d_in[11];
    const float* bias_h = (const float*)d_in[12];
    float* out = (float*)d_out;

    char* ws = (char*)d_ws;
    _Float16* U1f  = (_Float16*)(ws + WS_U1F);
    _Float16* Uh1f = (_Float16*)(ws + WS_UH1F);
    _Float16* W2f  = (_Float16*)(ws + WS_W2);
    float* cx = (float*)(ws + WS_CX);
    float* ch = (float*)(ws + WS_CH);
    float* bb = (float*)(ws + WS_BB);

    // 8192 + 16384 + 98304 + 262144 = 385024 threads = 1504 blocks
    prep_kernel<<<1504, 256, 0, stream>>>(Ux, Vx, Uh0, Vh0, Uh1, Vh1,
                                          dia_x, dia_h, bias_x, bias_h,
                                          U1f, Uh1f, W2f, cx, ch, bb);
    fused_kernel<<<256, 1024, 0, stream>>>(x, h, c, U1f, Uh1f, W2f,
                                           cx, ch, bb, out);
}